// Round 6
// baseline (382.430 us; speedup 1.0000x reference)
//
#include <hip/hip_runtime.h>
#include <hip/hip_bf16.h>

// GCN 2-layer. CSR via block-local radix partition, 16-padded lists (dummy node N).
// R5: h' = UNSCALED x@W1; agg1 applies isd[src] per edge (scalar loads).
// R6: gemm2 fused into agg1's epilogue -- each wave finishes its node's h1 row in
//     registers, spills it to per-wave LDS, and computes the 128->40 matvec
//     h2'[n] = isd_n * (relu(h1) @ W2) in-wave (W2 fp32 transposed in LDS,
//     stride-133 conflict-free). h1 never materializes (-51MB traffic, -1 launch).
//     4 dispatches: f1(part||prep) -> f2(place||gemm1) -> agg1g2 -> agg2.

#define CHUNK   4096              // edges per partition block (392 blocks)
#define NPB     512               // nodes per bucket (dst >> 9)
#define NBUCK   196               // ceil(100000/512)
#define BBCAP   9216              // bucket capacity (mean 8163, +11 sigma)

typedef __bf16 bf16x8 __attribute__((ext_vector_type(8)));
typedef float floatx4 __attribute__((ext_vector_type(4)));

__device__ inline unsigned short f2bf(float f) {      // RNE fp32->bf16
    unsigned u = __float_as_uint(f);
    u += 0x7FFF + ((u >> 16) & 1);
    return (unsigned short)(u >> 16);
}
__device__ inline float bflo(unsigned p) { return __uint_as_float(p << 16); }
__device__ inline float bfhi(unsigned p) { return __uint_as_float(p & 0xFFFF0000u); }

// ---------------- F1: radix partition  ||  W1 prep ----------------
// part blocks [0,nchunk); prep blocks [nchunk, nchunk+16)
__global__ __launch_bounds__(256) void k_f1(const int* __restrict__ src,
                                            const int* __restrict__ dst,
                                            int* __restrict__ gcursor,
                                            unsigned* __restrict__ buckets,
                                            int E, int nchunk,
                                            const float* __restrict__ W1,
                                            unsigned short* __restrict__ w1s,
                                            unsigned* __restrict__ h2z) {
    int t = threadIdx.x;
    if ((int)blockIdx.x >= nchunk) {
        // ---- prep_w1: W1 -> bf16 MFMA B-fragment order; zero h2' dummy row ----
        int pb = blockIdx.x - nchunk;
        if (pb == 0 && t < 36) h2z[t] = 0;            // row N + slack
        int flat = pb * 256 + t;                      // 0..4095
        int kt = flat >> 9;
        int nt = (flat >> 6) & 7;
        int lane = flat & 63;
        int kbase = kt * 32 + ((lane >> 4) << 3);
        int n = nt * 16 + (lane & 15);
        unsigned short v[8];
        #pragma unroll
        for (int j = 0; j < 8; ++j) v[j] = f2bf(W1[(size_t)(kbase + j) * 128 + n]);
        unsigned short* d = &w1s[(size_t)flat * 8];
        *(short4*)(d)     = make_short4(v[0], v[1], v[2], v[3]);
        *(short4*)(d + 4) = make_short4(v[4], v[5], v[6], v[7]);
        return;
    }
    // ---- partition: rec = src (17b) | (dst&511)<<17, bucket = dst>>9 ----
    __shared__ unsigned srec[CHUNK];          // 16 KB
    __shared__ unsigned char sb8[CHUNK];      // 4 KB
    __shared__ int hist[NBUCK];
    __shared__ int lbase[NBUCK];
    __shared__ int gbase[NBUCK];
    __shared__ int scanbuf[256];
    int base = blockIdx.x * CHUNK;
    int cnt = min(CHUNK, E - base);           // multiple of 4
    for (int i = t; i < NBUCK; i += 256) hist[i] = 0;
    __syncthreads();

    unsigned rec[16];
    unsigned br[16];                          // b (8b) | rank<<8
    bool valid[4];
    #pragma unroll
    for (int k = 0; k < 4; ++k) {
        int e0 = k * 1024 + t * 4;
        valid[k] = (e0 < cnt);
        if (valid[k]) {
            int4 s4 = *(const int4*)&src[base + e0];
            int4 d4 = *(const int4*)&dst[base + e0];
            int ss[4] = {s4.x, s4.y, s4.z, s4.w};
            int dd[4] = {d4.x, d4.y, d4.z, d4.w};
            #pragma unroll
            for (int j = 0; j < 4; ++j) {
                int b = dd[j] >> 9;
                int r = atomicAdd(&hist[b], 1);           // LDS atomic
                rec[k * 4 + j] = (unsigned)ss[j] | ((unsigned)(dd[j] & 511) << 17);
                br[k * 4 + j] = (unsigned)b | ((unsigned)r << 8);
            }
        }
    }
    __syncthreads();
    // inclusive Hillis-Steele scan over 256 (NBUCK padded)
    scanbuf[t] = (t < NBUCK) ? hist[t] : 0;
    __syncthreads();
    for (int s = 1; s < 256; s <<= 1) {
        int v = (t >= s) ? scanbuf[t - s] : 0;
        __syncthreads();
        scanbuf[t] += v;
        __syncthreads();
    }
    if (t < NBUCK) {
        lbase[t] = scanbuf[t] - hist[t];                  // exclusive base
        gbase[t] = atomicAdd(&gcursor[t], hist[t]);       // per-bucket global atomic
    }
    __syncthreads();
    // reorder into LDS, grouped by bucket
    #pragma unroll
    for (int k = 0; k < 4; ++k) {
        if (valid[k]) {
            #pragma unroll
            for (int j = 0; j < 4; ++j) {
                unsigned b = br[k * 4 + j] & 255u;
                unsigned r = br[k * 4 + j] >> 8;
                int p = lbase[b] + (int)r;
                srec[p] = rec[k * 4 + j];
                sb8[p] = (unsigned char)b;
            }
        }
    }
    __syncthreads();
    // dense flat write
    for (int i = t; i < cnt; i += 256) {
        int b = sb8[i];
        int pos = gbase[b] + (i - lbase[b]);
        if (pos < BBCAP) buckets[(size_t)b * BBCAP + pos] = srec[i];
    }
}

// ---------------- F2: count+isd+offsets+place (block-local)  ||  GEMM1 ----------------
// place blocks [0,NBUCK): LDS histogram of own bucket -> deg/isd/offsets -> CSR fill.
// gemm1 blocks [NBUCK, NBUCK+G1): h'[N+1,128](bf16) = x @ W1 (UNSCALED).
__global__ __launch_bounds__(256) void k_f2(const unsigned* __restrict__ buckets,
                                            const int* __restrict__ gcursor,
                                            int* __restrict__ deg,
                                            int* __restrict__ counter,
                                            int* __restrict__ offsets,
                                            float* __restrict__ isd,
                                            int* __restrict__ csr,
                                            const float* __restrict__ X,
                                            const unsigned short* __restrict__ w1s,
                                            unsigned short* __restrict__ H, int N) {
    __shared__ __align__(16) unsigned char SH[16384];
    int tid = threadIdx.x;
    if ((int)blockIdx.x < NBUCK) {
        int* s_deg = (int*)SH;                 // [512] degree histogram
        int* s_off = (int*)(SH + 2048);        // [512] absolute start offsets
        int* cur   = (int*)(SH + 4096);        // [512] live cursors
        int* sb    = (int*)(SH + 6144);        // [256] scan buffer
        int* sbase = (int*)(SH + 7168);        // [1]
        int b = blockIdx.x;
        int node0 = b << 9;
        int cnt = min(gcursor[b], BBCAP);
        const unsigned* bk = &buckets[(size_t)b * BBCAP];
        // pass 1: block-local degree histogram
        for (int i = tid; i < NPB; i += 256) s_deg[i] = 0;
        __syncthreads();
        for (int i = tid; i < cnt; i += 256)
            atomicAdd(&s_deg[bk[i] >> 17], 1);
        __syncthreads();
        // padded prefix scan over 512 node degrees (2 per thread)
        int i0 = tid * 2;
        int na = node0 + i0, nb = node0 + i0 + 1;
        int da = s_deg[i0], db = s_deg[i0 + 1];
        if (na >= N) da = 0;
        if (nb >= N) db = 0;
        int dpa = (da + 15) & ~15, dpb = (db + 15) & ~15;
        sb[tid] = dpa + dpb;
        __syncthreads();
        for (int s = 1; s < 256; s <<= 1) {
            int v = (tid >= s) ? sb[tid - s] : 0;
            __syncthreads();
            sb[tid] += v;
            __syncthreads();
        }
        int excl = sb[tid] - (dpa + dpb);
        if (tid == 0) *sbase = atomicAdd(counter, sb[255]);
        if (b == 0 && tid == 1) isd[N] = 0.f;          // dummy node
        __syncthreads();
        int offa = *sbase + excl;
        int offb = offa + dpa;
        if (na < N) {
            deg[na] = da; offsets[na] = offa;
            isd[na] = (da > 0) ? rsqrtf((float)da) : 0.f;
        }
        if (nb < N) {
            deg[nb] = db; offsets[nb] = offb;
            isd[nb] = (db > 0) ? rsqrtf((float)db) : 0.f;
        }
        s_off[i0] = offa; s_off[i0 + 1] = offb;
        s_deg[i0] = da;   s_deg[i0 + 1] = db;
        cur[i0] = offa;   cur[i0 + 1] = offb;
        __syncthreads();
        // pass 2: CSR fill
        for (int i = tid; i < cnt; i += 256) {
            unsigned r = bk[i];
            int p = atomicAdd(&cur[r >> 17], 1);
            csr[p] = (int)(r & 0x1FFFFu);
        }
        __syncthreads();
        // fill pad region with dummy node N (h'[N] = 0, h2'[N] = 0)
        for (int i = tid; i < NPB; i += 256) {
            int n = node0 + i;
            if (n < N) {
                int d = s_deg[i];
                int st = s_off[i] + d;
                int en = s_off[i] + ((d + 15) & ~15);
                for (int p = st; p < en; ++p) csr[p] = N;
            }
        }
        return;
    }
    // ---- GEMM1 (unscaled): h'[N+1,128](bf16) = x @ W1, MFMA 16x16x32 ----
    unsigned short* smem = (unsigned short*)SH;
    unsigned short* sA = smem;
    unsigned short* sB = smem + 2048;
    int lane = tid & 63;
    int wave = tid >> 6;
    int wr = wave >> 1;
    int wc = wave & 1;
    int m0 = (blockIdx.x - NBUCK) * 64;

    floatx4 acc[2][4] = {};

    for (int kt = 0; kt < 8; ++kt) {
        #pragma unroll
        for (int i = 0; i < 2; ++i) {
            int f = tid * 2 + i;
            int row = f >> 3;
            int c4 = (f & 7) * 4;
            float4 v = make_float4(0.f, 0.f, 0.f, 0.f);
            int grow = m0 + row;
            if (grow < N) v = *(const float4*)&X[(size_t)grow * 256 + kt * 32 + c4];
            int mt = row >> 4;
            int flane = (row & 15) | ((c4 >> 3) << 4);
            int j0 = c4 & 7;
            unsigned short* d = &sA[(size_t)(mt * 64 + flane) * 8 + j0];
            *(short4*)d = make_short4(f2bf(v.x), f2bf(v.y), f2bf(v.z), f2bf(v.w));
        }
        {
            const float4* srcp = (const float4*)&w1s[(size_t)kt * 4096];
            float4* dstp = (float4*)sB;
            dstp[tid] = srcp[tid];
            dstp[tid + 256] = srcp[tid + 256];
        }
        __syncthreads();
        bf16x8 a[2], b[4];
        #pragma unroll
        for (int p = 0; p < 2; ++p)
            a[p] = *(const bf16x8*)&sA[(size_t)((wr * 2 + p) * 64 + lane) * 8];
        #pragma unroll
        for (int q = 0; q < 4; ++q)
            b[q] = *(const bf16x8*)&sB[(size_t)((wc * 4 + q) * 64 + lane) * 8];
        #pragma unroll
        for (int p = 0; p < 2; ++p)
            #pragma unroll
            for (int q = 0; q < 4; ++q)
                acc[p][q] = __builtin_amdgcn_mfma_f32_16x16x32_bf16(a[p], b[q], acc[p][q], 0, 0, 0);
        __syncthreads();
    }
    #pragma unroll
    for (int p = 0; p < 2; ++p)
        #pragma unroll
        for (int q = 0; q < 4; ++q)
            #pragma unroll
            for (int r = 0; r < 4; ++r) {
                int rl = wr * 32 + p * 16 + ((lane >> 4) << 2) + r;
                int c = wc * 64 + q * 16 + (lane & 15);
                smem[rl * 128 + c] = f2bf(acc[p][q][r]);
            }
    __syncthreads();
    #pragma unroll
    for (int i = 0; i < 4; ++i) {
        int f = tid + i * 256;
        int row = f >> 4;
        int c8 = (f & 15) * 8;
        int grow = m0 + row;
        if (grow <= N)   // row N = zeros (A-tile zeros for grow>=N)
            *(float4*)&H[(size_t)grow * 128 + c8] = *(const float4*)&smem[row * 128 + c8];
    }
}

// ---------------- agg1+gemm2 fused ----------------
// Per wave: gather h1[n] = relu(b1 + isd_n * sum isd_src * h'[src]) (fp32 in regs),
// spill row to per-wave LDS, compute h2'[n][c] = isd_n * dot(h1, W2[:,c]) per lane.
// W2 staged fp32 transposed in LDS, stride 133 (conflict-free scalar col reads).
__global__ __launch_bounds__(1024) void k_agg1g2(const unsigned* __restrict__ Hu,
                                                 const int* __restrict__ csr,
                                                 const float* __restrict__ isd,
                                                 const int* __restrict__ offsets,
                                                 const int* __restrict__ deg,
                                                 const float* __restrict__ b1,
                                                 const float* __restrict__ W2,
                                                 unsigned short* __restrict__ H2s,
                                                 int N) {
    __shared__ float sW2t[40 * 133];      // W2^T, [c][k], stride 133 words
    __shared__ float h1row[16 * 128];     // per-wave h1 row (fp32)
    int tid = threadIdx.x;
    // stage W2 transposed: coalesced float4 reads (40 % 4 == 0 -> no row straddle)
    for (int j = tid; j < 1280; j += 1024) {
        float4 v = *(const float4*)&W2[(size_t)j * 4];
        int c0 = (4 * j) % 40;
        int k  = (4 * j) / 40;
        sW2t[(c0 + 0) * 133 + k] = v.x;
        sW2t[(c0 + 1) * 133 + k] = v.y;
        sW2t[(c0 + 2) * 133 + k] = v.z;
        sW2t[(c0 + 3) * 133 + k] = v.w;
    }
    __syncthreads();

    int wv = tid >> 6;                    // wave 0..15
    int lane = tid & 63;
    int node = __builtin_amdgcn_readfirstlane(blockIdx.x * 16 + wv);
    bool live = (node < N);
    int start = 0, nb = 0;
    float isdn = 0.f;
    if (live) {
        start = offsets[node];
        nb = (deg[node] + 15) >> 4;
        isdn = isd[node];
    }
    float acc0 = 0.f, acc1 = 0.f;
    for (int ib = 0; ib < nb; ++ib) {
        int b0 = start + ib * 16;
        int s[16];
        #pragma unroll
        for (int j = 0; j < 16; ++j) s[j] = csr[b0 + j];        // scalar loads
        float iss[16];
        #pragma unroll
        for (int j = 0; j < 16; ++j) iss[j] = isd[s[j]];        // scalar loads (isd[N]=0)
        unsigned p[16];
        #pragma unroll
        for (int j = 0; j < 16; ++j) p[j] = Hu[(size_t)s[j] * 64 + lane];
        #pragma unroll
        for (int j = 0; j < 16; ++j) {
            acc0 = fmaf(iss[j], bflo(p[j]), acc0);
            acc1 = fmaf(iss[j], bfhi(p[j]), acc1);
        }
    }
    // h1 row (post-bias, relu), spill to this wave's LDS slice
    float r0 = fmaxf(fmaf(isdn, acc0, b1[2 * lane]), 0.f);
    float r1 = fmaxf(fmaf(isdn, acc1, b1[2 * lane + 1]), 0.f);
    float* hr = &h1row[wv * 128];
    *(float2*)&hr[2 * lane] = make_float2(r0, r1);
    asm volatile("s_waitcnt lgkmcnt(0)" ::: "memory");   // wave-local LDS RAW fence
    // matvec: lane c computes h2'[node][c]
    int cc = (lane < 40) ? lane : 0;
    const float* wcol = &sW2t[cc * 133];
    float s0 = 0.f, s1 = 0.f, s2 = 0.f, s3 = 0.f;
    #pragma unroll
    for (int kb = 0; kb < 32; ++kb) {
        float4 hv = *(const float4*)&hr[kb * 4];         // wave-uniform broadcast
        s0 = fmaf(hv.x, wcol[4 * kb + 0], s0);
        s1 = fmaf(hv.y, wcol[4 * kb + 1], s1);
        s2 = fmaf(hv.z, wcol[4 * kb + 2], s2);
        s3 = fmaf(hv.w, wcol[4 * kb + 3], s3);
    }
    float hv2 = (s0 + s1) + (s2 + s3);
    if (live && lane < 40)
        H2s[(size_t)node * 40 + lane] = f2bf(hv2 * isdn);
}

// ---------------- agg2: out = b2 + isdn * sum h2'[src] , C=40 ----------------
__global__ __launch_bounds__(256) void k_agg2(const unsigned* __restrict__ Hu2,
                                              const int* __restrict__ csr,
                                              const float* __restrict__ isd,
                                              const int* __restrict__ offsets,
                                              const int* __restrict__ deg,
                                              const float* __restrict__ b2,
                                              float* __restrict__ out, int N) {
    int node = __builtin_amdgcn_readfirstlane((blockIdx.x * blockDim.x + threadIdx.x) >> 6);
    int lane = threadIdx.x & 63;
    if (node >= N) return;
    int start = offsets[node];
    int nb = (deg[node] + 15) >> 4;
    float isdn = isd[node];
    int sub = lane >> 5;       // 0/1
    int c = lane & 31;         // active c<20; c in [20,32) reads slack (finite, unused)
    float acc0 = 0.f, acc1 = 0.f;
    for (int ib = 0; ib < nb; ++ib) {
        int b0 = start + ib * 16;
        #pragma unroll
        for (int j = 0; j < 8; ++j) {
            int s = csr[b0 + (j << 1) + sub];
            unsigned q = Hu2[(size_t)s * 20 + c];
            acc0 += bflo(q);
            acc1 += bfhi(q);
        }
    }
    acc0 += __shfl(acc0, lane + 32);
    acc1 += __shfl(acc1, lane + 32);
    if (lane < 20)
        *(float2*)&out[(size_t)node * 40 + 2 * lane] =
            make_float2(fmaf(isdn, acc0, b2[2 * lane]), fmaf(isdn, acc1, b2[2 * lane + 1]));
}

extern "C" void kernel_launch(void* const* d_in, const int* in_sizes, int n_in,
                              void* d_out, int out_size, void* d_ws, size_t ws_size,
                              hipStream_t stream) {
    const float* x  = (const float*)d_in[0];
    const int*  src = (const int*)d_in[1];
    const int*  dst = (const int*)d_in[2];
    const float* W1 = (const float*)d_in[3];
    const float* b1 = (const float*)d_in[4];
    const float* W2 = (const float*)d_in[5];
    const float* b2 = (const float*)d_in[6];
    float* out = (float*)d_out;

    const int N = in_sizes[0] / 256;   // 100000
    const int E = in_sizes[1];         // 1600000

    char* w = (char*)d_ws;
    auto alloc = [&](size_t bytes) -> void* {
        void* p = (void*)w;
        w += (bytes + 15) & ~(size_t)15;
        return p;
    };
    int*      gcursor = (int*)alloc(256 * 4);                 // zeroed
    int*      counter = (int*)alloc(16);                      // zeroed
    int*      deg     = (int*)alloc((size_t)N * 4);           // written by f2
    float*    isd     = (float*)alloc((size_t)(N + 1) * 4);
    int*      offsets = (int*)alloc((size_t)(N + 1) * 4);
    unsigned* buckets = (unsigned*)alloc((size_t)NBUCK * BBCAP * 4);
    int*      csr     = (int*)alloc((size_t)(E + 16 * (size_t)N) * 4);
    unsigned short* w1s = (unsigned short*)alloc(32768 * 2);
    unsigned short* h   = (unsigned short*)alloc((size_t)(N + 1) * 128 * 2);  // h'
    unsigned short* h2  = (unsigned short*)alloc(((size_t)(N + 1) * 20 + 16) * 4);  // h2'

    hipMemsetAsync(gcursor, 0, 256 * 4 + 16, stream);

    int nchunk = (E + CHUNK - 1) / CHUNK;   // 392
    int G1 = (N + 63) / 64;                 // 1563
    k_f1<<<nchunk + 16, 256, 0, stream>>>(src, dst, gcursor, buckets, E, nchunk,
                                          W1, w1s, (unsigned*)h2 + (size_t)N * 20);
    k_f2<<<NBUCK + G1, 256, 0, stream>>>(buckets, gcursor, deg, counter, offsets, isd,
                                         csr, x, w1s, h, N);
    k_agg1g2<<<(N + 15) / 16, 1024, 0, stream>>>((const unsigned*)h, csr, isd, offsets,
                                                 deg, b1, W2, h2, N);
    k_agg2<<<(N + 3) / 4, 256, 0, stream>>>((const unsigned*)h2, csr, isd, offsets, deg,
                                            b2, out, N);
}

// Round 8
// 344.493 us; speedup vs baseline: 1.1101x; 1.1101x over previous
//
#include <hip/hip_runtime.h>
#include <hip/hip_bf16.h>

// GCN 2-layer. CSR via block-local radix partition, 16-padded lists (dummy node N).
// R5: h' = UNSCALED x@W1; agg1 applies isd[src] per edge (scalar loads).
// R7/R8: R6 fusion reverted (LDS-bound epilogue). gemm2 rebuilt as MFMA with exact
//     W2 = bf16(hi) + bf16(lo) split (fp32-accurate weights, 2 MFMA accumulations).
//     B-fragments for W2 prebuilt in f1's prep region. gemm2: ~47us LDS-bound ->
//     ~10us memory-bound. 5 dispatches: f1 -> f2(place||gemm1) -> agg1 -> gemm2 -> agg2.
//     (R7 bench was an infra failure; R8 = identical resubmit.)

#define CHUNK   4096              // edges per partition block (392 blocks)
#define NPB     512               // nodes per bucket (dst >> 9)
#define NBUCK   196               // ceil(100000/512)
#define BBCAP   9216              // bucket capacity (mean 8163, +11 sigma)

typedef __bf16 bf16x8 __attribute__((ext_vector_type(8)));
typedef float floatx4 __attribute__((ext_vector_type(4)));

__device__ inline unsigned short f2bf(float f) {      // RNE fp32->bf16
    unsigned u = __float_as_uint(f);
    u += 0x7FFF + ((u >> 16) & 1);
    return (unsigned short)(u >> 16);
}
__device__ inline float bflo(unsigned p) { return __uint_as_float(p << 16); }
__device__ inline float bfhi(unsigned p) { return __uint_as_float(p & 0xFFFF0000u); }

// ---------------- F1: radix partition  ||  W1/W2 prep ----------------
// part blocks [0,nchunk); w1 prep [nchunk, nchunk+16); w2 prep [nchunk+16, nchunk+22)
__global__ __launch_bounds__(256) void k_f1(const int* __restrict__ src,
                                            const int* __restrict__ dst,
                                            int* __restrict__ gcursor,
                                            unsigned* __restrict__ buckets,
                                            int E, int nchunk,
                                            const float* __restrict__ W1,
                                            unsigned short* __restrict__ w1s,
                                            const float* __restrict__ W2,
                                            unsigned short* __restrict__ w2f,
                                            unsigned* __restrict__ h2z) {
    int t = threadIdx.x;
    if ((int)blockIdx.x >= nchunk + 16) {
        // ---- prep_w2: W2 -> bf16 hi/lo MFMA B-fragments [term][kt][nt][lane][8] ----
        int flat2 = (blockIdx.x - nchunk - 16) * 256 + t;   // 0..1535
        int term = flat2 >= 768;
        int u = term ? flat2 - 768 : flat2;
        int kt = u / 192;            // 0..3
        int rm = u - kt * 192;
        int nt = rm >> 6;            // 0..2
        int lane = rm & 63;
        unsigned short vv[8];
        #pragma unroll
        for (int j = 0; j < 8; ++j) {
            int k = kt * 32 + ((lane >> 4) << 3) + j;
            int c = nt * 16 + (lane & 15);
            float wv = (c < 40) ? W2[(size_t)k * 40 + c] : 0.f;
            unsigned short hi = f2bf(wv);
            if (term == 0) vv[j] = hi;
            else vv[j] = f2bf(wv - __uint_as_float((unsigned)hi << 16));
        }
        unsigned short* d = &w2f[(size_t)flat2 * 8];
        *(short4*)(d)     = make_short4(vv[0], vv[1], vv[2], vv[3]);
        *(short4*)(d + 4) = make_short4(vv[4], vv[5], vv[6], vv[7]);
        return;
    }
    if ((int)blockIdx.x >= nchunk) {
        // ---- prep_w1: W1 -> bf16 MFMA B-fragment order; zero h2' dummy row ----
        int pb = blockIdx.x - nchunk;
        if (pb == 0 && t < 36) h2z[t] = 0;            // row N + slack
        int flat = pb * 256 + t;                      // 0..4095
        int kt = flat >> 9;
        int nt = (flat >> 6) & 7;
        int lane = flat & 63;
        int kbase = kt * 32 + ((lane >> 4) << 3);
        int n = nt * 16 + (lane & 15);
        unsigned short v[8];
        #pragma unroll
        for (int j = 0; j < 8; ++j) v[j] = f2bf(W1[(size_t)(kbase + j) * 128 + n]);
        unsigned short* d = &w1s[(size_t)flat * 8];
        *(short4*)(d)     = make_short4(v[0], v[1], v[2], v[3]);
        *(short4*)(d + 4) = make_short4(v[4], v[5], v[6], v[7]);
        return;
    }
    // ---- partition: rec = src (17b) | (dst&511)<<17, bucket = dst>>9 ----
    __shared__ unsigned srec[CHUNK];          // 16 KB
    __shared__ unsigned char sb8[CHUNK];      // 4 KB
    __shared__ int hist[NBUCK];
    __shared__ int lbase[NBUCK];
    __shared__ int gbase[NBUCK];
    __shared__ int scanbuf[256];
    int base = blockIdx.x * CHUNK;
    int cnt = min(CHUNK, E - base);           // multiple of 4
    for (int i = t; i < NBUCK; i += 256) hist[i] = 0;
    __syncthreads();

    unsigned rec[16];
    unsigned br[16];                          // b (8b) | rank<<8
    bool valid[4];
    #pragma unroll
    for (int k = 0; k < 4; ++k) {
        int e0 = k * 1024 + t * 4;
        valid[k] = (e0 < cnt);
        if (valid[k]) {
            int4 s4 = *(const int4*)&src[base + e0];
            int4 d4 = *(const int4*)&dst[base + e0];
            int ss[4] = {s4.x, s4.y, s4.z, s4.w};
            int dd[4] = {d4.x, d4.y, d4.z, d4.w};
            #pragma unroll
            for (int j = 0; j < 4; ++j) {
                int b = dd[j] >> 9;
                int r = atomicAdd(&hist[b], 1);           // LDS atomic
                rec[k * 4 + j] = (unsigned)ss[j] | ((unsigned)(dd[j] & 511) << 17);
                br[k * 4 + j] = (unsigned)b | ((unsigned)r << 8);
            }
        }
    }
    __syncthreads();
    // inclusive Hillis-Steele scan over 256 (NBUCK padded)
    scanbuf[t] = (t < NBUCK) ? hist[t] : 0;
    __syncthreads();
    for (int s = 1; s < 256; s <<= 1) {
        int v = (t >= s) ? scanbuf[t - s] : 0;
        __syncthreads();
        scanbuf[t] += v;
        __syncthreads();
    }
    if (t < NBUCK) {
        lbase[t] = scanbuf[t] - hist[t];                  // exclusive base
        gbase[t] = atomicAdd(&gcursor[t], hist[t]);       // per-bucket global atomic
    }
    __syncthreads();
    // reorder into LDS, grouped by bucket
    #pragma unroll
    for (int k = 0; k < 4; ++k) {
        if (valid[k]) {
            #pragma unroll
            for (int j = 0; j < 4; ++j) {
                unsigned b = br[k * 4 + j] & 255u;
                unsigned r = br[k * 4 + j] >> 8;
                int p = lbase[b] + (int)r;
                srec[p] = rec[k * 4 + j];
                sb8[p] = (unsigned char)b;
            }
        }
    }
    __syncthreads();
    // dense flat write
    for (int i = t; i < cnt; i += 256) {
        int b = sb8[i];
        int pos = gbase[b] + (i - lbase[b]);
        if (pos < BBCAP) buckets[(size_t)b * BBCAP + pos] = srec[i];
    }
}

// ---------------- F2: count+isd+offsets+place (block-local)  ||  GEMM1 ----------------
__global__ __launch_bounds__(256) void k_f2(const unsigned* __restrict__ buckets,
                                            const int* __restrict__ gcursor,
                                            int* __restrict__ deg,
                                            int* __restrict__ counter,
                                            int* __restrict__ offsets,
                                            float* __restrict__ isd,
                                            int* __restrict__ csr,
                                            const float* __restrict__ X,
                                            const unsigned short* __restrict__ w1s,
                                            unsigned short* __restrict__ H, int N) {
    __shared__ __align__(16) unsigned char SH[16384];
    int tid = threadIdx.x;
    if ((int)blockIdx.x < NBUCK) {
        int* s_deg = (int*)SH;                 // [512] degree histogram
        int* s_off = (int*)(SH + 2048);        // [512] absolute start offsets
        int* cur   = (int*)(SH + 4096);        // [512] live cursors
        int* sb    = (int*)(SH + 6144);        // [256] scan buffer
        int* sbase = (int*)(SH + 7168);        // [1]
        int b = blockIdx.x;
        int node0 = b << 9;
        int cnt = min(gcursor[b], BBCAP);
        const unsigned* bk = &buckets[(size_t)b * BBCAP];
        // pass 1: block-local degree histogram
        for (int i = tid; i < NPB; i += 256) s_deg[i] = 0;
        __syncthreads();
        for (int i = tid; i < cnt; i += 256)
            atomicAdd(&s_deg[bk[i] >> 17], 1);
        __syncthreads();
        // padded prefix scan over 512 node degrees (2 per thread)
        int i0 = tid * 2;
        int na = node0 + i0, nb = node0 + i0 + 1;
        int da = s_deg[i0], db = s_deg[i0 + 1];
        if (na >= N) da = 0;
        if (nb >= N) db = 0;
        int dpa = (da + 15) & ~15, dpb = (db + 15) & ~15;
        sb[tid] = dpa + dpb;
        __syncthreads();
        for (int s = 1; s < 256; s <<= 1) {
            int v = (tid >= s) ? sb[tid - s] : 0;
            __syncthreads();
            sb[tid] += v;
            __syncthreads();
        }
        int excl = sb[tid] - (dpa + dpb);
        if (tid == 0) *sbase = atomicAdd(counter, sb[255]);
        if (b == 0 && tid == 1) isd[N] = 0.f;          // dummy node
        __syncthreads();
        int offa = *sbase + excl;
        int offb = offa + dpa;
        if (na < N) {
            deg[na] = da; offsets[na] = offa;
            isd[na] = (da > 0) ? rsqrtf((float)da) : 0.f;
        }
        if (nb < N) {
            deg[nb] = db; offsets[nb] = offb;
            isd[nb] = (db > 0) ? rsqrtf((float)db) : 0.f;
        }
        s_off[i0] = offa; s_off[i0 + 1] = offb;
        s_deg[i0] = da;   s_deg[i0 + 1] = db;
        cur[i0] = offa;   cur[i0 + 1] = offb;
        __syncthreads();
        // pass 2: CSR fill
        for (int i = tid; i < cnt; i += 256) {
            unsigned r = bk[i];
            int p = atomicAdd(&cur[r >> 17], 1);
            csr[p] = (int)(r & 0x1FFFFu);
        }
        __syncthreads();
        // fill pad region with dummy node N (h'[N] = 0, h2'[N] = 0)
        for (int i = tid; i < NPB; i += 256) {
            int n = node0 + i;
            if (n < N) {
                int d = s_deg[i];
                int st = s_off[i] + d;
                int en = s_off[i] + ((d + 15) & ~15);
                for (int p = st; p < en; ++p) csr[p] = N;
            }
        }
        return;
    }
    // ---- GEMM1 (unscaled): h'[N+1,128](bf16) = x @ W1, MFMA 16x16x32 ----
    unsigned short* smem = (unsigned short*)SH;
    unsigned short* sA = smem;
    unsigned short* sB = smem + 2048;
    int lane = tid & 63;
    int wave = tid >> 6;
    int wr = wave >> 1;
    int wc = wave & 1;
    int m0 = (blockIdx.x - NBUCK) * 64;

    floatx4 acc[2][4] = {};

    for (int kt = 0; kt < 8; ++kt) {
        #pragma unroll
        for (int i = 0; i < 2; ++i) {
            int f = tid * 2 + i;
            int row = f >> 3;
            int c4 = (f & 7) * 4;
            float4 v = make_float4(0.f, 0.f, 0.f, 0.f);
            int grow = m0 + row;
            if (grow < N) v = *(const float4*)&X[(size_t)grow * 256 + kt * 32 + c4];
            int mt = row >> 4;
            int flane = (row & 15) | ((c4 >> 3) << 4);
            int j0 = c4 & 7;
            unsigned short* d = &sA[(size_t)(mt * 64 + flane) * 8 + j0];
            *(short4*)d = make_short4(f2bf(v.x), f2bf(v.y), f2bf(v.z), f2bf(v.w));
        }
        {
            const float4* srcp = (const float4*)&w1s[(size_t)kt * 4096];
            float4* dstp = (float4*)sB;
            dstp[tid] = srcp[tid];
            dstp[tid + 256] = srcp[tid + 256];
        }
        __syncthreads();
        bf16x8 a[2], b[4];
        #pragma unroll
        for (int p = 0; p < 2; ++p)
            a[p] = *(const bf16x8*)&sA[(size_t)((wr * 2 + p) * 64 + lane) * 8];
        #pragma unroll
        for (int q = 0; q < 4; ++q)
            b[q] = *(const bf16x8*)&sB[(size_t)((wc * 4 + q) * 64 + lane) * 8];
        #pragma unroll
        for (int p = 0; p < 2; ++p)
            #pragma unroll
            for (int q = 0; q < 4; ++q)
                acc[p][q] = __builtin_amdgcn_mfma_f32_16x16x32_bf16(a[p], b[q], acc[p][q], 0, 0, 0);
        __syncthreads();
    }
    #pragma unroll
    for (int p = 0; p < 2; ++p)
        #pragma unroll
        for (int q = 0; q < 4; ++q)
            #pragma unroll
            for (int r = 0; r < 4; ++r) {
                int rl = wr * 32 + p * 16 + ((lane >> 4) << 2) + r;
                int c = wc * 64 + q * 16 + (lane & 15);
                smem[rl * 128 + c] = f2bf(acc[p][q][r]);
            }
    __syncthreads();
    #pragma unroll
    for (int i = 0; i < 4; ++i) {
        int f = tid + i * 256;
        int row = f >> 4;
        int c8 = (f & 15) * 8;
        int grow = m0 + row;
        if (grow <= N)   // row N = zeros (A-tile zeros for grow>=N)
            *(float4*)&H[(size_t)grow * 128 + c8] = *(const float4*)&smem[row * 128 + c8];
    }
}

// ---------------- agg1: h1 = relu(b1 + isd_dst * sum isd_src * h'[src]) ----------------
__global__ __launch_bounds__(256) void k_agg1(const unsigned* __restrict__ Hu,
                                              const int* __restrict__ csr,
                                              const float* __restrict__ isd,
                                              const int* __restrict__ offsets,
                                              const int* __restrict__ deg,
                                              const float* __restrict__ b1,
                                              unsigned* __restrict__ H1u, int N) {
    int node = __builtin_amdgcn_readfirstlane((blockIdx.x * blockDim.x + threadIdx.x) >> 6);
    int lane = threadIdx.x & 63;
    if (node >= N) return;
    int start = offsets[node];
    int nb = (deg[node] + 15) >> 4;
    float isdn = isd[node];
    float acc0 = 0.f, acc1 = 0.f;
    for (int ib = 0; ib < nb; ++ib) {
        int b0 = start + ib * 16;
        int s[16];
        #pragma unroll
        for (int j = 0; j < 16; ++j) s[j] = csr[b0 + j];        // scalar loads
        float iss[16];
        #pragma unroll
        for (int j = 0; j < 16; ++j) iss[j] = isd[s[j]];        // scalar loads (isd[N]=0)
        unsigned p[16];
        #pragma unroll
        for (int j = 0; j < 16; ++j) p[j] = Hu[(size_t)s[j] * 64 + lane];
        #pragma unroll
        for (int j = 0; j < 16; ++j) {
            acc0 = fmaf(iss[j], bflo(p[j]), acc0);
            acc1 = fmaf(iss[j], bfhi(p[j]), acc1);
        }
    }
    float r0 = fmaxf(fmaf(isdn, acc0, b1[2 * lane]), 0.f);
    float r1 = fmaxf(fmaf(isdn, acc1, b1[2 * lane + 1]), 0.f);
    H1u[(size_t)node * 64 + lane] = (unsigned)f2bf(r0) | ((unsigned)f2bf(r1) << 16);
}

// ---------------- GEMM2 (MFMA): h2'[N+1,40](bf16) = isd*(h1 @ (W2hi+W2lo)) ----------------
// A = 64x128 h1 tile staged in fragment layout (pure uint4 moves, h1 already bf16).
// B = prebuilt w2f fragments [term][kt][nt][lane][8]. 24 MFMA/wave. Epilogue via
// padded LDS transpose -> coalesced 80B row writes.
__global__ __launch_bounds__(256) void k_gemm2(const unsigned short* __restrict__ H1,
                                               const unsigned short* __restrict__ w2f,
                                               const float* __restrict__ isd,
                                               unsigned short* __restrict__ H2s, int N) {
    __shared__ __align__(16) unsigned short sA[8192];     // 16KB [kt][mt][lane][8]
    __shared__ __align__(16) unsigned short sC[64 * 56];  // 7KB, stride 56 (112B, 16-aligned)
    int tid = threadIdx.x;
    int block_row = blockIdx.x * 64;
    #pragma unroll
    for (int i = 0; i < 4; ++i) {
        int f = tid + i * 256;
        int row = f >> 4;
        int c8 = (f & 15) * 8;
        uint4 v = make_uint4(0, 0, 0, 0);
        int grow = block_row + row;
        if (grow < N) v = *(const uint4*)&H1[(size_t)grow * 128 + c8];
        int kt = c8 >> 5;
        int g  = (c8 >> 3) & 3;
        int mt = row >> 4;
        *(uint4*)&sA[(size_t)((((kt << 2) + mt) << 6) + ((row & 15) | (g << 4))) * 8] = v;
    }
    __syncthreads();
    int wr = tid >> 6;            // wave = mtile
    int lane = tid & 63;
    floatx4 acc[3] = {};
    #pragma unroll
    for (int kt = 0; kt < 4; ++kt) {
        bf16x8 a = *(const bf16x8*)&sA[(size_t)((((kt << 2) + wr) << 6) + lane) * 8];
        #pragma unroll
        for (int nt = 0; nt < 3; ++nt) {
            bf16x8 bh = *(const bf16x8*)&w2f[(size_t)((kt * 3 + nt) * 64 + lane) * 8];
            bf16x8 bl = *(const bf16x8*)&w2f[(size_t)(768 + (kt * 3 + nt) * 64 + lane) * 8];
            acc[nt] = __builtin_amdgcn_mfma_f32_16x16x32_bf16(a, bh, acc[nt], 0, 0, 0);
            acc[nt] = __builtin_amdgcn_mfma_f32_16x16x32_bf16(a, bl, acc[nt], 0, 0, 0);
        }
    }
    // scale rows by isd, pack to sC (C layout: col=lane&15, row=(lane>>4)*4+r)
    #pragma unroll
    for (int r = 0; r < 4; ++r) {
        int row = wr * 16 + ((lane >> 4) << 2) + r;
        int g = block_row + row;
        float sc = isd[g > N ? N : g];
        #pragma unroll
        for (int nt = 0; nt < 3; ++nt)
            sC[row * 56 + nt * 16 + (lane & 15)] = f2bf(acc[nt][r] * sc);
    }
    __syncthreads();
    if (tid < 64) {
        int grow = block_row + tid;
        if (grow < N) {
            #pragma unroll
            for (int j = 0; j < 5; ++j)
                *(uint4*)&H2s[(size_t)grow * 40 + j * 8] = *(const uint4*)&sC[tid * 56 + j * 8];
        }
    }
}

// ---------------- agg2: out = b2 + isdn * sum h2'[src] , C=40 ----------------
__global__ __launch_bounds__(256) void k_agg2(const unsigned* __restrict__ Hu2,
                                              const int* __restrict__ csr,
                                              const float* __restrict__ isd,
                                              const int* __restrict__ offsets,
                                              const int* __restrict__ deg,
                                              const float* __restrict__ b2,
                                              float* __restrict__ out, int N) {
    int node = __builtin_amdgcn_readfirstlane((blockIdx.x * blockDim.x + threadIdx.x) >> 6);
    int lane = threadIdx.x & 63;
    if (node >= N) return;
    int start = offsets[node];
    int nb = (deg[node] + 15) >> 4;
    float isdn = isd[node];
    int sub = lane >> 5;       // 0/1
    int c = lane & 31;         // active c<20; c in [20,32) reads slack (finite, unused)
    float acc0 = 0.f, acc1 = 0.f;
    for (int ib = 0; ib < nb; ++ib) {
        int b0 = start + ib * 16;
        #pragma unroll
        for (int j = 0; j < 8; ++j) {
            int s = csr[b0 + (j << 1) + sub];
            unsigned q = Hu2[(size_t)s * 20 + c];
            acc0 += bflo(q);
            acc1 += bfhi(q);
        }
    }
    acc0 += __shfl(acc0, lane + 32);
    acc1 += __shfl(acc1, lane + 32);
    if (lane < 20)
        *(float2*)&out[(size_t)node * 40 + 2 * lane] =
            make_float2(fmaf(isdn, acc0, b2[2 * lane]), fmaf(isdn, acc1, b2[2 * lane + 1]));
}

extern "C" void kernel_launch(void* const* d_in, const int* in_sizes, int n_in,
                              void* d_out, int out_size, void* d_ws, size_t ws_size,
                              hipStream_t stream) {
    const float* x  = (const float*)d_in[0];
    const int*  src = (const int*)d_in[1];
    const int*  dst = (const int*)d_in[2];
    const float* W1 = (const float*)d_in[3];
    const float* b1 = (const float*)d_in[4];
    const float* W2 = (const float*)d_in[5];
    const float* b2 = (const float*)d_in[6];
    float* out = (float*)d_out;

    const int N = in_sizes[0] / 256;   // 100000
    const int E = in_sizes[1];         // 1600000

    char* w = (char*)d_ws;
    auto alloc = [&](size_t bytes) -> void* {
        void* p = (void*)w;
        w += (bytes + 15) & ~(size_t)15;
        return p;
    };
    int*      gcursor = (int*)alloc(256 * 4);                 // zeroed
    int*      counter = (int*)alloc(16);                      // zeroed
    int*      deg     = (int*)alloc((size_t)N * 4);           // written by f2
    float*    isd     = (float*)alloc((size_t)(N + 1) * 4);
    int*      offsets = (int*)alloc((size_t)(N + 1) * 4);
    unsigned* buckets = (unsigned*)alloc((size_t)NBUCK * BBCAP * 4);
    int*      csr     = (int*)alloc((size_t)(E + 16 * (size_t)N) * 4);
    unsigned short* w1s = (unsigned short*)alloc(32768 * 2);
    unsigned short* w2f = (unsigned short*)alloc(12288 * 2);  // [2][4][3][64][8] bf16
    unsigned short* h   = (unsigned short*)alloc((size_t)(N + 1) * 128 * 2);  // h'
    unsigned short* h1  = (unsigned short*)alloc((size_t)N * 128 * 2);
    unsigned short* h2  = (unsigned short*)alloc(((size_t)(N + 1) * 20 + 16) * 4);  // h2'

    hipMemsetAsync(gcursor, 0, 256 * 4 + 16, stream);

    int nchunk = (E + CHUNK - 1) / CHUNK;   // 392
    int G1 = (N + 63) / 64;                 // 1563
    k_f1<<<nchunk + 22, 256, 0, stream>>>(src, dst, gcursor, buckets, E, nchunk,
                                          W1, w1s, W2, w2f,
                                          (unsigned*)h2 + (size_t)N * 20);
    k_f2<<<NBUCK + G1, 256, 0, stream>>>(buckets, gcursor, deg, counter, offsets, isd,
                                         csr, x, w1s, h, N);
    k_agg1<<<(N + 3) / 4, 256, 0, stream>>>((const unsigned*)h, csr, isd, offsets, deg,
                                            b1, (unsigned*)h1, N);
    k_gemm2<<<G1, 256, 0, stream>>>(h1, w2f, isd, h2, N);
    k_agg2<<<(N + 3) / 4, 256, 0, stream>>>((const unsigned*)h2, csr, isd, offsets, deg,
                                            b2, out, N);
}